// Round 2
// baseline (168.727 us; speedup 1.0000x reference)
//
#include <hip/hip_runtime.h>

typedef unsigned short u16;
typedef __attribute__((ext_vector_type(4))) float f32x4;
typedef __attribute__((ext_vector_type(4))) int i32x4;
typedef __attribute__((ext_vector_type(8))) short short8;
typedef __attribute__((ext_vector_type(8))) __bf16 bf16x8;
typedef __attribute__((ext_vector_type(4))) unsigned short u16x4;

#define BATCH 16384
#define NINP 256
#define HID 1024
#define NOUT 16

// ---------- helpers ----------
__device__ __forceinline__ u16 f2bf(float f) {
  unsigned u = __builtin_bit_cast(unsigned, f);
  u += 0x7FFFu + ((u >> 16) & 1u);   // round-to-nearest-even
  return (u16)(u >> 16);
}
__device__ __forceinline__ f32x4 mfma_s8(short8 a, short8 b, f32x4 c) {
  return __builtin_amdgcn_mfma_f32_16x16x32_bf16(
      __builtin_bit_cast(bf16x8, a), __builtin_bit_cast(bf16x8, b), c, 0, 0, 0);
}
__device__ __forceinline__ f32x4 mfma_bb(bf16x8 a, bf16x8 b, f32x4 c) {
  return __builtin_amdgcn_mfma_f32_16x16x32_bf16(a, b, c, 0, 0, 0);
}
__device__ __forceinline__ void gload_lds16(const void* g, void* l) {
  __builtin_amdgcn_global_load_lds(
      (const __attribute__((address_space(1))) void*)g,
      (__attribute__((address_space(3))) void*)l, 16, 0, 0);
}

// ---------- workspace layout (bytes) ----------
static const size_t OFF_H0   = 0;          // 33,554,432  H0 bf16 [16384][1024]
static const size_t OFF_H1   = 33554432;   // 33,554,432  H1 bf16
static const size_t OFF_XB   = 33554432;   //  8,388,608  x bf16 (aliases H1: dead before gemm2 writes H1)
static const size_t OFF_W0T  = 67108864;   //    524,288  W0^T bf16 [1024][256]
static const size_t OFF_W1T  = 67633152;   //  2,097,152  W1^T bf16 [1024][1024]
static const size_t OFF_W2T  = 69730304;   //     32,768  W2^T bf16 [16][1024]
static const size_t OFF_UW2T = 69763072;   //    524,288  uw2t bf16 [256][32 o][32 f]
static const size_t OFF_UW3P = 70287360;   //    262,144  uw3p bf16 [256][16 o2][32 slot]
static const size_t OFF_CB   = 70549504;   //        256  cb f32 [16]
static const size_t OFF_PART = 70549760;   //  8,388,608  part f32 [8][16384][16]

// ---------- fused elementwise converts ----------
__global__ __launch_bounds__(256) void k_convert(
    const float* __restrict__ x, const float* __restrict__ uw2,
    const float* __restrict__ uw3, const float* __restrict__ b2,
    const float* __restrict__ ub3,
    u16* __restrict__ xb, u16* __restrict__ uw2t, u16* __restrict__ uw3p,
    float* __restrict__ cb)
{
  const int bid = blockIdx.x;
  if (bid < 4096) {                       // x -> bf16, 4 elems/thread
    const int idx = (bid * 256 + threadIdx.x) * 4;
    const float4 v = *(const float4*)&x[idx];
    u16x4 o4 = { f2bf(v.x), f2bf(v.y), f2bf(v.z), f2bf(v.w) };
    *(u16x4*)&xb[idx] = o4;
  } else if (bid < 4352) {                // uw2t[i][o][f] = uw2[i][f][o]
    const int e = ((bid - 4096) * 256 + threadIdx.x) * 4;
    const float4 v = *(const float4*)&uw2[e];
    const int i = e >> 10, f = (e >> 5) & 31, o = e & 31;
    u16* d = &uw2t[i * 1024 + o * 32 + f];
    d[0] = f2bf(v.x); d[32] = f2bf(v.y); d[64] = f2bf(v.z); d[96] = f2bf(v.w);
  } else if (bid < 4480) {                // uw3p[i][o2][slot(f)] = uw3[i][f][o2]
    const int e = ((bid - 4352) * 256 + threadIdx.x) * 4;
    const float4 v = *(const float4*)&uw3[e];
    const int i = e >> 9, f = (e >> 4) & 31, o2 = e & 15;
    // k-slot permutation: slot (g,j): j<4 -> o=4g+j ; j>=4 -> o=16+4g+(j-4)
    const int s = (f < 16) ? (((f >> 2) << 3) + (f & 3))
                           : ((((f - 16) >> 2) << 3) + 4 + (f & 3));
    u16* d = &uw3p[i * 512 + o2 * 32 + s];
    d[0] = f2bf(v.x); d[32] = f2bf(v.y); d[64] = f2bf(v.z); d[96] = f2bf(v.w);
  } else {                                // cb[o] = b2[o] + sum_i ub3[i][o]
    const int t = threadIdx.x;
    if (t < 16) {
      float s = b2[t];
      for (int i = 0; i < 256; ++i) s += ub3[i * 16 + t];
      cb[t] = s;
    }
  }
}

// ---------- LDS-tiled transpose f32 [K][N] -> bf16 [N][K], all 3 weights ----------
__global__ __launch_bounds__(256) void k_transpose(
    const float* __restrict__ W0, const float* __restrict__ W1,
    const float* __restrict__ W2,
    u16* __restrict__ W0T, u16* __restrict__ W1T, u16* __restrict__ W2T)
{
  __shared__ float tile[32][33];
  const int bid = blockIdx.x;
  const float* src; u16* dst; int K, N, kb, ob;
  if (bid < 256)       { src = W0; dst = W0T; K = 256;  N = 1024; int t = bid;        kb = (t & 7) * 32;  ob = (t >> 3) * 32; }
  else if (bid < 1280) { src = W1; dst = W1T; K = 1024; N = 1024; int t = bid - 256;  kb = (t & 31) * 32; ob = (t >> 5) * 32; }
  else                 { src = W2; dst = W2T; K = 1024; N = 16;   int t = bid - 1280; kb = t * 32;        ob = 0; }
  const int tx = threadIdx.x & 31, ty = threadIdx.x >> 5;
  for (int r = ty; r < 32; r += 8)
    if (ob + tx < N) tile[r][tx] = src[(size_t)(kb + r) * N + ob + tx];
  __syncthreads();
  for (int r = ty; r < 32; r += 8)
    if (ob + r < N) dst[(size_t)(ob + r) * K + kb + tx] = f2bf(tile[tx][r]);
}

// ---------- MFMA GEMM: C = relu(A @ B^T + bias), bf16 in/out, fp32 acc ----------
__global__ __launch_bounds__(256, 2) void k_gemm(
    const u16* __restrict__ A, const u16* __restrict__ BT,
    const float* __restrict__ bias, u16* __restrict__ C,
    int M, int N, int K)
{
  const int tid = threadIdx.x;
  const int lane = tid & 63, wid = tid >> 6;
  const int l15 = lane & 15, g = lane >> 4;
  const int nbn = N >> 7;
  const int nwg = gridDim.x;
  int logical = blockIdx.x;
  if ((nwg & 7) == 0) {                       // bijective XCD swizzle
    const int q = nwg >> 3;
    logical = (logical & 7) * q + (logical >> 3);
  }
  const int bm = logical / nbn, bn = logical % nbn;
  const size_t rb = (size_t)bm * 128, cbase = (size_t)bn * 128;

  __shared__ __align__(16) u16 As[128 * 32];
  __shared__ __align__(16) u16 Bs[128 * 32];

  const int wr = (wid >> 1) * 64, wc = (wid & 1) * 64;
  f32x4 acc[4][4] = {};

  for (int kt = 0; kt < K; kt += 32) {
#pragma unroll
    for (int it = 0; it < 2; ++it) {
      const int s = it * 256 + tid;
      const int row = s >> 2, kc = s & 3;
      gload_lds16(&A[(rb + row) * K + kt + kc * 8], &As[s * 8]);
      gload_lds16(&BT[(cbase + row) * K + kt + kc * 8], &Bs[s * 8]);
    }
    __syncthreads();
    short8 a[4], b[4];
#pragma unroll
    for (int m = 0; m < 4; ++m)
      a[m] = *(const short8*)&As[(wr + m * 16 + l15) * 32 + g * 8];
#pragma unroll
    for (int n = 0; n < 4; ++n)
      b[n] = *(const short8*)&Bs[(wc + n * 16 + l15) * 32 + g * 8];
#pragma unroll
    for (int m = 0; m < 4; ++m)
#pragma unroll
      for (int n = 0; n < 4; ++n)
        acc[m][n] = mfma_s8(a[m], b[n], acc[m][n]);
    __syncthreads();
  }

#pragma unroll
  for (int n = 0; n < 4; ++n) {
    const int col = (int)cbase + wc + n * 16 + l15;
    const float bv = bias[col];
#pragma unroll
    for (int m = 0; m < 4; ++m) {
#pragma unroll
      for (int r = 0; r < 4; ++r) {
        const int row = (int)rb + wr + m * 16 + g * 4 + r;
        float v = acc[m][n][r] + bv;
        v = fmaxf(v, 0.f);
        C[(size_t)row * N + col] = f2bf(v);
      }
    }
  }
}

// ---------- uni MLPs + final layer (H1 @ W2^T), 8 chunks ----------
// grid = 2048: blockIdx = rowblk*8 + chunk. Block = 4 waves x 16 batch rows.
// chunk owns features [32c, 32c+32) and K-range [128c, 128c+128) of H1@W2.
// All inner-loop MFMAs are operand-swapped: D[out][batch], lane: b = lane&15,
// out = 4*(lane>>4)+r. No LDS traffic in the feature loop.
__global__ __launch_bounds__(256) void k_uni(
    const float* __restrict__ x,
    const float* __restrict__ uw1, const float* __restrict__ ub1,
    const u16* __restrict__ uw2t, const float* __restrict__ ub2,
    const u16* __restrict__ uw3p,
    const u16* __restrict__ H1, const u16* __restrict__ W2T,
    float* __restrict__ part)
{
  const int tid = threadIdx.x, lane = tid & 63, wid = tid >> 6;
  const int l15 = lane & 15, g = lane >> 4;
  const int chunk = blockIdx.x & 7, rowblk = blockIdx.x >> 3;
  const int rb_blk = rowblk * 64;
  const int rb = rb_blk + wid * 16;
  const int i0 = chunk * 32;

  __shared__ __align__(16) float xt[64][36];   // x tile f32, padded (36*4B stride)

  {
    const int r0 = tid >> 3, c4 = (tid & 7) * 4;
    const float4 v0 = *(const float4*)&x[(size_t)(rb_blk + r0) * NINP + i0 + c4];
    const float4 v1 = *(const float4*)&x[(size_t)(rb_blk + 32 + r0) * NINP + i0 + c4];
    *(float4*)&xt[r0][c4] = v0;
    *(float4*)&xt[32 + r0][c4] = v1;
  }
  __syncthreads();

  f32x4 acc = {0.f, 0.f, 0.f, 0.f};
  const f32x4 zero4 = {0.f, 0.f, 0.f, 0.f};
  const float* xrow = &xt[wid * 16 + l15][0];

#pragma unroll 2
  for (int ii = 0; ii < 32; ++ii) {
    const int i = i0 + ii;
    const float xv = xrow[ii];

    // layer 1 (rank-1) in f32; lane (g,l15) -> h1[b=l15][f=g*8+j]  (B-frag)
    const float4 w1lo = *(const float4*)&uw1[i * 32 + g * 8];
    const float4 w1hi = *(const float4*)&uw1[i * 32 + g * 8 + 4];
    const float4 b1lo = *(const float4*)&ub1[i * 32 + g * 8];
    const float4 b1hi = *(const float4*)&ub1[i * 32 + g * 8 + 4];
    bf16x8 af;
    af[0] = (__bf16)fmaxf(fmaf(xv, w1lo.x, b1lo.x), 0.f);
    af[1] = (__bf16)fmaxf(fmaf(xv, w1lo.y, b1lo.y), 0.f);
    af[2] = (__bf16)fmaxf(fmaf(xv, w1lo.z, b1lo.z), 0.f);
    af[3] = (__bf16)fmaxf(fmaf(xv, w1lo.w, b1lo.w), 0.f);
    af[4] = (__bf16)fmaxf(fmaf(xv, w1hi.x, b1hi.x), 0.f);
    af[5] = (__bf16)fmaxf(fmaf(xv, w1hi.y, b1hi.y), 0.f);
    af[6] = (__bf16)fmaxf(fmaf(xv, w1hi.z, b1hi.z), 0.f);
    af[7] = (__bf16)fmaxf(fmaf(xv, w1hi.w, b1hi.w), 0.f);

    // layer 2 swapped: D2[o][b] = uw2t-as-A @ h1-as-B
    const bf16x8 bv0 = __builtin_bit_cast(bf16x8,
        *(const i32x4*)&uw2t[(size_t)i * 1024 + l15 * 32 + g * 8]);
    const bf16x8 bv1 = __builtin_bit_cast(bf16x8,
        *(const i32x4*)&uw2t[(size_t)i * 1024 + (16 + l15) * 32 + g * 8]);
    f32x4 d0 = mfma_bb(bv0, af, zero4);   // o = 4g+r      (rows 0..15)
    f32x4 d1 = mfma_bb(bv1, af, zero4);   // o = 16+4g+r   (rows 16..31)

    // h2 = relu(D2 + ub2[i]); stays lane-local (b=l15), k-slots per uw3p perm
    const float4 bb0 = *(const float4*)&ub2[i * 32 + g * 4];
    const float4 bb1 = *(const float4*)&ub2[i * 32 + 16 + g * 4];
    bf16x8 h2;
    h2[0] = (__bf16)fmaxf(d0[0] + bb0.x, 0.f);
    h2[1] = (__bf16)fmaxf(d0[1] + bb0.y, 0.f);
    h2[2] = (__bf16)fmaxf(d0[2] + bb0.z, 0.f);
    h2[3] = (__bf16)fmaxf(d0[3] + bb0.w, 0.f);
    h2[4] = (__bf16)fmaxf(d1[0] + bb1.x, 0.f);
    h2[5] = (__bf16)fmaxf(d1[1] + bb1.y, 0.f);
    h2[6] = (__bf16)fmaxf(d1[2] + bb1.z, 0.f);
    h2[7] = (__bf16)fmaxf(d1[3] + bb1.w, 0.f);

    // layer 3 swapped: acc[o2][b] += uw3p-as-A @ h2-as-B
    const bf16x8 b3 = __builtin_bit_cast(bf16x8,
        *(const i32x4*)&uw3p[(size_t)i * 512 + l15 * 32 + g * 8]);
    acc = mfma_bb(b3, h2, acc);
  }

  // final-layer K-chunk, swapped to match acc layout: acc[o2][b] += W2T @ H1^T
  {
    const int kb0 = chunk * 128;
#pragma unroll
    for (int kk = 0; kk < 4; ++kk) {
      const int kb = kb0 + kk * 32;
      const bf16x8 av = __builtin_bit_cast(bf16x8,
          *(const i32x4*)&H1[(size_t)(rb + l15) * HID + kb + g * 8]);
      const bf16x8 bv = __builtin_bit_cast(bf16x8,
          *(const i32x4*)&W2T[l15 * HID + kb + g * 8]);
      acc = mfma_bb(bv, av, acc);
    }
  }

  // acc[r] = u[b=l15][o2=4g+r] -> contiguous f32x4 store
  float* p = part + ((size_t)chunk * BATCH + rb) * NOUT;
  *(f32x4*)&p[l15 * 16 + g * 4] = acc;
}

// ---------- reduce 8 partials + cb -> out ----------
__global__ __launch_bounds__(256) void k_reduce(
    const float* __restrict__ part, const float* __restrict__ cb,
    float* __restrict__ out)
{
  const int j4 = blockIdx.x * 256 + threadIdx.x;   // 65536 float4's
  const float4 c = ((const float4*)cb)[j4 & 3];
  const float4* p = (const float4*)part;
  float rx = c.x, ry = c.y, rz = c.z, rw = c.w;
#pragma unroll
  for (int cc = 0; cc < 8; ++cc) {
    const float4 a = p[cc * 65536 + j4];
    rx += a.x; ry += a.y; rz += a.z; rw += a.w;
  }
  float4 r; r.x = rx; r.y = ry; r.z = rz; r.w = rw;
  ((float4*)out)[j4] = r;
}

extern "C" void kernel_launch(void* const* d_in, const int* in_sizes, int n_in,
                              void* d_out, int out_size, void* d_ws, size_t ws_size,
                              hipStream_t stream) {
  (void)in_sizes; (void)n_in; (void)out_size; (void)ws_size;
  const float* x   = (const float*)d_in[0];
  const float* W0  = (const float*)d_in[1];
  const float* b0  = (const float*)d_in[2];
  const float* W1  = (const float*)d_in[3];
  const float* b1  = (const float*)d_in[4];
  const float* W2  = (const float*)d_in[5];
  const float* b2  = (const float*)d_in[6];
  const float* uw1 = (const float*)d_in[7];
  const float* ub1 = (const float*)d_in[8];
  const float* uw2 = (const float*)d_in[9];
  const float* ub2 = (const float*)d_in[10];
  const float* uw3 = (const float*)d_in[11];
  const float* ub3 = (const float*)d_in[12];
  float* out = (float*)d_out;

  char* ws = (char*)d_ws;
  u16*   H0   = (u16*)(ws + OFF_H0);
  u16*   H1   = (u16*)(ws + OFF_H1);
  u16*   xb   = (u16*)(ws + OFF_XB);
  u16*   W0T  = (u16*)(ws + OFF_W0T);
  u16*   W1T  = (u16*)(ws + OFF_W1T);
  u16*   W2T  = (u16*)(ws + OFF_W2T);
  u16*   uw2t = (u16*)(ws + OFF_UW2T);
  u16*   uw3p = (u16*)(ws + OFF_UW3P);
  float* cb   = (float*)(ws + OFF_CB);
  float* part = (float*)(ws + OFF_PART);

  k_convert<<<4481, 256, 0, stream>>>(x, uw2, uw3, b2, ub3, xb, uw2t, uw3p, cb);
  k_transpose<<<1312, 256, 0, stream>>>(W0, W1, W2, W0T, W1T, W2T);
  k_gemm<<<1024, 256, 0, stream>>>(xb, W0T, b0, H0, BATCH, HID, NINP);
  k_gemm<<<1024, 256, 0, stream>>>(H0, W1T, b1, H1, BATCH, HID, HID);
  k_uni<<<2048, 256, 0, stream>>>(x, uw1, ub1, uw2t, ub2, uw3p, H1, W2T, part);
  k_reduce<<<256, 256, 0, stream>>>(part, cb, out);
}

// Round 3
// 114.515 us; speedup vs baseline: 1.4734x; 1.4734x over previous
//
#include <hip/hip_runtime.h>

typedef unsigned short u16;
typedef __attribute__((ext_vector_type(4))) float f32x4;
typedef __attribute__((ext_vector_type(4))) int i32x4;
typedef __attribute__((ext_vector_type(8))) short short8;
typedef __attribute__((ext_vector_type(8))) __bf16 bf16x8;
typedef __attribute__((ext_vector_type(4))) unsigned short u16x4;

#define BATCH 16384
#define NINP 256
#define HID 1024
#define NOUT 16

// ---------- helpers ----------
__device__ __forceinline__ u16 f2bf(float f) {
  unsigned u = __builtin_bit_cast(unsigned, f);
  u += 0x7FFFu + ((u >> 16) & 1u);   // round-to-nearest-even
  return (u16)(u >> 16);
}
__device__ __forceinline__ f32x4 mfma_s8(short8 a, short8 b, f32x4 c) {
  return __builtin_amdgcn_mfma_f32_16x16x32_bf16(
      __builtin_bit_cast(bf16x8, a), __builtin_bit_cast(bf16x8, b), c, 0, 0, 0);
}
__device__ __forceinline__ f32x4 mfma_bb(bf16x8 a, bf16x8 b, f32x4 c) {
  return __builtin_amdgcn_mfma_f32_16x16x32_bf16(a, b, c, 0, 0, 0);
}
__device__ __forceinline__ void gload_lds16(const void* g, void* l) {
  __builtin_amdgcn_global_load_lds(
      (const __attribute__((address_space(1))) void*)g,
      (__attribute__((address_space(3))) void*)l, 16, 0, 0);
}

// ---------- workspace layout (bytes) ----------
static const size_t OFF_H0   = 0;          // 33,554,432  H0 bf16 [16384][1024]
static const size_t OFF_H1   = 33554432;   // 33,554,432  H1 bf16
static const size_t OFF_XB   = 33554432;   //  8,388,608  x bf16 (aliases H1: dead before gemm2 writes H1)
static const size_t OFF_W0T  = 67108864;   //    524,288  W0^T bf16 [1024][256]
static const size_t OFF_W1T  = 67633152;   //  2,097,152  W1^T bf16 [1024][1024]
static const size_t OFF_W2T  = 69730304;   //     32,768  W2^T bf16 [16][1024]
static const size_t OFF_UWP  = 69763072;   //  1,048,576  packed uni blobs, 4096B/feature
static const size_t OFF_CB   = 70811648;   //        256  cb f32 [16]
static const size_t OFF_PART = 70811904;   //  8,388,608  part f32 [8][16384][16]

// Blob layout per feature i (byte offsets within uwp + i*4096):
//    0..128   uw1[32] f32
//  128..256   ub1[32] f32
//  256..384   ub2[32] f32
//  384..512   pad
//  512..1536  puw2 lo=0: lane L holds uw2t[row=L&15      ][col=(L>>4)*8+j], j=0..7 bf16
// 1536..2560  puw2 lo=1: lane L holds uw2t[row=16+(L&15) ][col=(L>>4)*8+j]
// 2560..3584  puw3:      lane L holds uw3p[o2=L&15][slot=(L>>4)*8+j]
// 3584..4096  pad

// ---------- merged prep: transposes + converts + packing ----------
__global__ __launch_bounds__(256) void k_prep(
    const float* __restrict__ x,
    const float* __restrict__ W0, const float* __restrict__ W1,
    const float* __restrict__ W2,
    const float* __restrict__ uw1, const float* __restrict__ ub1,
    const float* __restrict__ uw2, const float* __restrict__ ub2,
    const float* __restrict__ uw3, const float* __restrict__ b2,
    const float* __restrict__ ub3,
    u16* __restrict__ xb,
    u16* __restrict__ W0T, u16* __restrict__ W1T, u16* __restrict__ W2T,
    char* __restrict__ uwp, float* __restrict__ cb)
{
  __shared__ float tile[32][33];
  const int bid = blockIdx.x;
  const int tid = threadIdx.x;

  if (bid < 1312) {                       // weight transposes f32[K][N] -> bf16[N][K]
    const float* src; u16* dst; int K, N, kb, ob;
    if (bid < 256)       { src = W0; dst = W0T; K = 256;  N = 1024; int t = bid;        kb = (t & 7) * 32;  ob = (t >> 3) * 32; }
    else if (bid < 1280) { src = W1; dst = W1T; K = 1024; N = 1024; int t = bid - 256;  kb = (t & 31) * 32; ob = (t >> 5) * 32; }
    else                 { src = W2; dst = W2T; K = 1024; N = 16;   int t = bid - 1280; kb = t * 32;        ob = 0; }
    const int tx = tid & 31, ty = tid >> 5;
    for (int r = ty; r < 32; r += 8)
      if (ob + tx < N) tile[r][tx] = src[(size_t)(kb + r) * N + ob + tx];
    __syncthreads();
    for (int r = ty; r < 32; r += 8)
      if (ob + r < N) dst[(size_t)(ob + r) * K + kb + tx] = f2bf(tile[tx][r]);
  } else if (bid < 5408) {                // x -> bf16
    const int idx = ((bid - 1312) * 256 + tid) * 4;
    const float4 v = *(const float4*)&x[idx];
    u16x4 o4 = { f2bf(v.x), f2bf(v.y), f2bf(v.z), f2bf(v.w) };
    *(u16x4*)&xb[idx] = o4;
  } else if (bid < 5664) {                // uw2 -> puw2 fragments
    const int e = ((bid - 5408) * 256 + tid) * 4;
    const float4 v = *(const float4*)&uw2[e];
    const int i = e >> 10, f = (e >> 5) & 31, o = e & 31;
    const float vv[4] = { v.x, v.y, v.z, v.w };
    u16* blob16 = (u16*)(uwp + (size_t)i * 4096);
#pragma unroll
    for (int d = 0; d < 4; ++d) {
      const int oo = o + d;
      const int lane = ((f >> 3) << 4) | (oo & 15);
      blob16[256 + (oo >> 4) * 512 + lane * 8 + (f & 7)] = f2bf(vv[d]);
    }
  } else if (bid < 5792) {                // uw3 -> puw3 fragments (k-slot perm)
    const int e = ((bid - 5664) * 256 + tid) * 4;
    const float4 v = *(const float4*)&uw3[e];
    const int i = e >> 9, f = (e >> 4) & 31, o2 = e & 15;
    const int s = (f < 16) ? (((f >> 2) << 3) + (f & 3))
                           : ((((f - 16) >> 2) << 3) + 4 + (f & 3));
    const float vv[4] = { v.x, v.y, v.z, v.w };
    u16* blob16 = (u16*)(uwp + (size_t)i * 4096);
#pragma unroll
    for (int d = 0; d < 4; ++d)
      blob16[1280 + ((s >> 3) * 16 + o2 + d) * 8 + (s & 7)] = f2bf(vv[d]);
  } else if (bid < 5816) {                // uw1/ub1/ub2 f32 copy into blobs
    const int e4 = (bid - 5792) * 256 + tid;      // float4 index, 0..6143
    const int i = e4 / 24, r4 = e4 % 24;
    const float* src = (r4 < 8)  ? &uw1[i * 32 + r4 * 4]
                     : (r4 < 16) ? &ub1[i * 32 + (r4 - 8) * 4]
                                 : &ub2[i * 32 + (r4 - 16) * 4];
    *(float4*)(uwp + (size_t)i * 4096 + r4 * 16) = *(const float4*)src;
  } else {                                // cb[o] = b2[o] + sum_i ub3[i][o]
    __shared__ float red[16][16];
    const int ig = tid >> 4, o = tid & 15;
    float s = 0.f;
#pragma unroll
    for (int k = 0; k < 16; ++k) s += ub3[(ig * 16 + k) * 16 + o];
    red[ig][o] = s;
    __syncthreads();
    if (tid < 16) {
      float t = b2[tid];
#pragma unroll
      for (int k = 0; k < 16; ++k) t += red[k][tid];
      cb[tid] = t;
    }
  }
}

// ---------- MFMA GEMM: C = relu(A @ B^T + bias), bf16 in/out, fp32 acc ----------
__global__ __launch_bounds__(256, 2) void k_gemm(
    const u16* __restrict__ A, const u16* __restrict__ BT,
    const float* __restrict__ bias, u16* __restrict__ C,
    int M, int N, int K)
{
  const int tid = threadIdx.x;
  const int lane = tid & 63, wid = tid >> 6;
  const int l15 = lane & 15, g = lane >> 4;
  const int nbn = N >> 7;
  const int nwg = gridDim.x;
  int logical = blockIdx.x;
  if ((nwg & 7) == 0) {                       // bijective XCD swizzle
    const int q = nwg >> 3;
    logical = (logical & 7) * q + (logical >> 3);
  }
  const int bm = logical / nbn, bn = logical % nbn;
  const size_t rb = (size_t)bm * 128, cbase = (size_t)bn * 128;

  __shared__ __align__(16) u16 As[128 * 32];
  __shared__ __align__(16) u16 Bs[128 * 32];

  const int wr = (wid >> 1) * 64, wc = (wid & 1) * 64;
  f32x4 acc[4][4] = {};

  for (int kt = 0; kt < K; kt += 32) {
#pragma unroll
    for (int it = 0; it < 2; ++it) {
      const int s = it * 256 + tid;
      const int row = s >> 2, kc = s & 3;
      gload_lds16(&A[(rb + row) * K + kt + kc * 8], &As[s * 8]);
      gload_lds16(&BT[(cbase + row) * K + kt + kc * 8], &Bs[s * 8]);
    }
    __syncthreads();
    short8 a[4], b[4];
#pragma unroll
    for (int m = 0; m < 4; ++m)
      a[m] = *(const short8*)&As[(wr + m * 16 + l15) * 32 + g * 8];
#pragma unroll
    for (int n = 0; n < 4; ++n)
      b[n] = *(const short8*)&Bs[(wc + n * 16 + l15) * 32 + g * 8];
#pragma unroll
    for (int m = 0; m < 4; ++m)
#pragma unroll
      for (int n = 0; n < 4; ++n)
        acc[m][n] = mfma_s8(a[m], b[n], acc[m][n]);
    __syncthreads();
  }

#pragma unroll
  for (int n = 0; n < 4; ++n) {
    const int col = (int)cbase + wc + n * 16 + l15;
    const float bv = bias[col];
#pragma unroll
    for (int m = 0; m < 4; ++m) {
#pragma unroll
      for (int r = 0; r < 4; ++r) {
        const int row = (int)rb + wr + m * 16 + g * 4 + r;
        float v = acc[m][n][r] + bv;
        v = fmaxf(v, 0.f);
        C[(size_t)row * N + col] = f2bf(v);
      }
    }
  }
}

// ---------- uni MLPs + final layer (H1 @ W2^T), 8 chunks ----------
// grid = 1024: blockIdx = rowblk*8 + chunk. 4 waves x 32 batch rows (2 frags).
// All MFMAs operand-swapped: D[out][batch]; b = lane&15, out = 4*(lane>>4)+r.
// Weights stream from fragment-packed blobs: every wave load is contiguous.
__global__ __launch_bounds__(256, 4) void k_uni(
    const float* __restrict__ x,
    const char* __restrict__ uwp,
    const u16* __restrict__ H1, const u16* __restrict__ W2T,
    float* __restrict__ part)
{
  const int tid = threadIdx.x, lane = tid & 63, wid = tid >> 6;
  const int l15 = lane & 15, g = lane >> 4;
  const int chunk = blockIdx.x & 7, rowblk = blockIdx.x >> 3;
  const int rb_blk = rowblk * 128;
  const int rb = rb_blk + wid * 32;
  const int i0 = chunk * 32;

  __shared__ __align__(16) float xt[128][36];   // x tile f32, padded
  {
    const int r0 = tid >> 3, c4 = (tid & 7) << 2;
#pragma unroll
    for (int rr = 0; rr < 128; rr += 32)
      *(float4*)&xt[rr + r0][c4] =
          *(const float4*)&x[(size_t)(rb_blk + rr + r0) * NINP + i0 + c4];
  }
  __syncthreads();

  const f32x4 zero4 = {0.f, 0.f, 0.f, 0.f};
  f32x4 acc0 = zero4, acc1 = zero4;
  const float* xr0 = &xt[wid * 32 + l15][0];
  const float* xr1 = &xt[wid * 32 + 16 + l15][0];
  const char* bp = uwp + (size_t)i0 * 4096;

#pragma unroll 2
  for (int ii = 0; ii < 32; ++ii, bp += 4096) {
    const float4 w1lo = *(const float4*)(bp + g * 32);
    const float4 w1hi = *(const float4*)(bp + g * 32 + 16);
    const float4 b1lo = *(const float4*)(bp + 128 + g * 32);
    const float4 b1hi = *(const float4*)(bp + 128 + g * 32 + 16);
    const float4 bb0  = *(const float4*)(bp + 256 + g * 16);
    const float4 bb1  = *(const float4*)(bp + 320 + g * 16);
    const bf16x8 bv0 = *(const bf16x8*)(bp + 512 + lane * 16);
    const bf16x8 bv1 = *(const bf16x8*)(bp + 1536 + lane * 16);
    const bf16x8 b3  = *(const bf16x8*)(bp + 2560 + lane * 16);
    const float xv0 = xr0[ii], xv1 = xr1[ii];

    // layer 1 (rank-1): h1[b][f=g*8+j] as B-frag, two batch frags
    bf16x8 af0, af1;
    af0[0] = (__bf16)fmaxf(fmaf(xv0, w1lo.x, b1lo.x), 0.f);
    af0[1] = (__bf16)fmaxf(fmaf(xv0, w1lo.y, b1lo.y), 0.f);
    af0[2] = (__bf16)fmaxf(fmaf(xv0, w1lo.z, b1lo.z), 0.f);
    af0[3] = (__bf16)fmaxf(fmaf(xv0, w1lo.w, b1lo.w), 0.f);
    af0[4] = (__bf16)fmaxf(fmaf(xv0, w1hi.x, b1hi.x), 0.f);
    af0[5] = (__bf16)fmaxf(fmaf(xv0, w1hi.y, b1hi.y), 0.f);
    af0[6] = (__bf16)fmaxf(fmaf(xv0, w1hi.z, b1hi.z), 0.f);
    af0[7] = (__bf16)fmaxf(fmaf(xv0, w1hi.w, b1hi.w), 0.f);
    af1[0] = (__bf16)fmaxf(fmaf(xv1, w1lo.x, b1lo.x), 0.f);
    af1[1] = (__bf16)fmaxf(fmaf(xv1, w1lo.y, b1lo.y), 0.f);
    af1[2] = (__bf16)fmaxf(fmaf(xv1, w1lo.z, b1lo.z), 0.f);
    af1[3] = (__bf16)fmaxf(fmaf(xv1, w1lo.w, b1lo.w), 0.f);
    af1[4] = (__bf16)fmaxf(fmaf(xv1, w1hi.x, b1hi.x), 0.f);
    af1[5] = (__bf16)fmaxf(fmaf(xv1, w1hi.y, b1hi.y), 0.f);
    af1[6] = (__bf16)fmaxf(fmaf(xv1, w1hi.z, b1hi.z), 0.f);
    af1[7] = (__bf16)fmaxf(fmaf(xv1, w1hi.w, b1hi.w), 0.f);

    // layer 2 swapped: D2[o][b], o = 4g+r (+16 for d1*)
    f32x4 d00 = mfma_bb(bv0, af0, zero4);
    f32x4 d10 = mfma_bb(bv1, af0, zero4);
    f32x4 d01 = mfma_bb(bv0, af1, zero4);
    f32x4 d11 = mfma_bb(bv1, af1, zero4);

    // h2 = relu(D2 + ub2), lane-local; k-slots match uw3p permutation
    bf16x8 h20, h21;
    h20[0] = (__bf16)fmaxf(d00[0] + bb0.x, 0.f);
    h20[1] = (__bf16)fmaxf(d00[1] + bb0.y, 0.f);
    h20[2] = (__bf16)fmaxf(d00[2] + bb0.z, 0.f);
    h20[3] = (__bf16)fmaxf(d00[3] + bb0.w, 0.f);
    h20[4] = (__bf16)fmaxf(d10[0] + bb1.x, 0.f);
    h20[5] = (__bf16)fmaxf(d10[1] + bb1.y, 0.f);
    h20[6] = (__bf16)fmaxf(d10[2] + bb1.z, 0.f);
    h20[7] = (__bf16)fmaxf(d10[3] + bb1.w, 0.f);
    h21[0] = (__bf16)fmaxf(d01[0] + bb0.x, 0.f);
    h21[1] = (__bf16)fmaxf(d01[1] + bb0.y, 0.f);
    h21[2] = (__bf16)fmaxf(d01[2] + bb0.z, 0.f);
    h21[3] = (__bf16)fmaxf(d01[3] + bb0.w, 0.f);
    h21[4] = (__bf16)fmaxf(d11[0] + bb1.x, 0.f);
    h21[5] = (__bf16)fmaxf(d11[1] + bb1.y, 0.f);
    h21[6] = (__bf16)fmaxf(d11[2] + bb1.z, 0.f);
    h21[7] = (__bf16)fmaxf(d11[3] + bb1.w, 0.f);

    // layer 3 swapped: acc[o2][b] += uw3p @ h2
    acc0 = mfma_bb(b3, h20, acc0);
    acc1 = mfma_bb(b3, h21, acc1);
  }

  // final-layer K-chunk: acc[o2][b] += W2T @ H1^T
  {
    const int kb0 = chunk * 128;
#pragma unroll
    for (int kk = 0; kk < 4; ++kk) {
      const int kb = kb0 + kk * 32;
      const bf16x8 a0 = __builtin_bit_cast(bf16x8,
          *(const i32x4*)&H1[(size_t)(rb + l15) * HID + kb + g * 8]);
      const bf16x8 a1 = __builtin_bit_cast(bf16x8,
          *(const i32x4*)&H1[(size_t)(rb + 16 + l15) * HID + kb + g * 8]);
      const bf16x8 bv = __builtin_bit_cast(bf16x8,
          *(const i32x4*)&W2T[l15 * HID + kb + g * 8]);
      acc0 = mfma_bb(bv, a0, acc0);
      acc1 = mfma_bb(bv, a1, acc1);
    }
  }

  // acc*[r] = u[b=l15(+16)][o2=4g+r] -> contiguous f32x4 stores
  float* p = part + ((size_t)chunk * BATCH + rb) * NOUT;
  *(f32x4*)&p[l15 * 16 + g * 4] = acc0;
  *(f32x4*)&p[(16 + l15) * 16 + g * 4] = acc1;
}

// ---------- reduce 8 partials + cb -> out ----------
__global__ __launch_bounds__(256) void k_reduce(
    const float* __restrict__ part, const float* __restrict__ cb,
    float* __restrict__ out)
{
  const int j4 = blockIdx.x * 256 + threadIdx.x;   // 65536 float4's
  const float4 c = ((const float4*)cb)[j4 & 3];
  const float4* p = (const float4*)part;
  float rx = c.x, ry = c.y, rz = c.z, rw = c.w;
#pragma unroll
  for (int cc = 0; cc < 8; ++cc) {
    const float4 a = p[cc * 65536 + j4];
    rx += a.x; ry += a.y; rz += a.z; rw += a.w;
  }
  float4 r; r.x = rx; r.y = ry; r.z = rz; r.w = rw;
  ((float4*)out)[j4] = r;
}

extern "C" void kernel_launch(void* const* d_in, const int* in_sizes, int n_in,
                              void* d_out, int out_size, void* d_ws, size_t ws_size,
                              hipStream_t stream) {
  (void)in_sizes; (void)n_in; (void)out_size; (void)ws_size;
  const float* x   = (const float*)d_in[0];
  const float* W0  = (const float*)d_in[1];
  const float* b0  = (const float*)d_in[2];
  const float* W1  = (const float*)d_in[3];
  const float* b1  = (const float*)d_in[4];
  const float* W2  = (const float*)d_in[5];
  const float* b2  = (const float*)d_in[6];
  const float* uw1 = (const float*)d_in[7];
  const float* ub1 = (const float*)d_in[8];
  const float* uw2 = (const float*)d_in[9];
  const float* ub2 = (const float*)d_in[10];
  const float* uw3 = (const float*)d_in[11];
  const float* ub3 = (const float*)d_in[12];
  float* out = (float*)d_out;

  char* ws = (char*)d_ws;
  u16*   H0   = (u16*)(ws + OFF_H0);
  u16*   H1   = (u16*)(ws + OFF_H1);
  u16*   xb   = (u16*)(ws + OFF_XB);
  u16*   W0T  = (u16*)(ws + OFF_W0T);
  u16*   W1T  = (u16*)(ws + OFF_W1T);
  u16*   W2T  = (u16*)(ws + OFF_W2T);
  char*  uwp  = (char*)(ws + OFF_UWP);
  float* cb   = (float*)(ws + OFF_CB);
  float* part = (float*)(ws + OFF_PART);

  k_prep<<<5817, 256, 0, stream>>>(x, W0, W1, W2, uw1, ub1, uw2, ub2, uw3,
                                   b2, ub3, xb, W0T, W1T, W2T, uwp, cb);
  k_gemm<<<1024, 256, 0, stream>>>(xb, W0T, b0, H0, BATCH, HID, NINP);
  k_gemm<<<1024, 256, 0, stream>>>(H0, W1T, b1, H1, BATCH, HID, HID);
  k_uni<<<1024, 256, 0, stream>>>(x, uwp, H1, W2T, part);
  k_reduce<<<256, 256, 0, stream>>>(part, cb, out);
}

// Round 4
// 114.030 us; speedup vs baseline: 1.4797x; 1.0043x over previous
//
#include <hip/hip_runtime.h>

typedef unsigned short u16;
typedef __attribute__((ext_vector_type(4))) float f32x4;
typedef __attribute__((ext_vector_type(4))) int i32x4;
typedef __attribute__((ext_vector_type(8))) short short8;
typedef __attribute__((ext_vector_type(8))) __bf16 bf16x8;
typedef __attribute__((ext_vector_type(4))) unsigned short u16x4;

#define BATCH 16384
#define NINP 256
#define HID 1024
#define NOUT 16

// ---------- helpers ----------
__device__ __forceinline__ u16 f2bf(float f) {
  unsigned u = __builtin_bit_cast(unsigned, f);
  u += 0x7FFFu + ((u >> 16) & 1u);   // round-to-nearest-even
  return (u16)(u >> 16);
}
__device__ __forceinline__ f32x4 mfma_s8(short8 a, short8 b, f32x4 c) {
  return __builtin_amdgcn_mfma_f32_16x16x32_bf16(
      __builtin_bit_cast(bf16x8, a), __builtin_bit_cast(bf16x8, b), c, 0, 0, 0);
}
__device__ __forceinline__ f32x4 mfma_bb(bf16x8 a, bf16x8 b, f32x4 c) {
  return __builtin_amdgcn_mfma_f32_16x16x32_bf16(a, b, c, 0, 0, 0);
}
__device__ __forceinline__ void gload_lds16(const void* g, void* l) {
  __builtin_amdgcn_global_load_lds(
      (const __attribute__((address_space(1))) void*)g,
      (__attribute__((address_space(3))) void*)l, 16, 0, 0);
}

// ---------- workspace layout (bytes) ----------
static const size_t OFF_H0   = 0;          // 33,554,432  H0 bf16 [16384][1024]
static const size_t OFF_H1   = 33554432;   // 33,554,432  H1 bf16
static const size_t OFF_XB   = 33554432;   //  8,388,608  x bf16 (aliases H1: dead before gemm2 writes H1)
static const size_t OFF_W0T  = 67108864;   //    524,288  W0^T bf16 [1024][256]
static const size_t OFF_W1T  = 67633152;   //  2,097,152  W1^T bf16 [1024][1024]
static const size_t OFF_W2T  = 69730304;   //     32,768  W2^T bf16 [16][1024]
static const size_t OFF_UWP  = 69763072;   //  1,048,576  packed uni blobs, 4096B/feature
static const size_t OFF_CB   = 70811648;   //        256  cb f32 [16]
static const size_t OFF_PART = 70811904;   //  8,388,608  part f32 [8][16384][16]

// Blob layout per feature i (byte offsets within uwp + i*4096):
//    0..128   uw1[32] f32
//  128..256   ub1[32] f32
//  256..384   ub2[32] f32
//  384..512   pad
//  512..1536  puw2 lo=0: lane L holds uw2t[row=L&15      ][col=(L>>4)*8+j], j=0..7 bf16
// 1536..2560  puw2 lo=1: lane L holds uw2t[row=16+(L&15) ][col=(L>>4)*8+j]
// 2560..3584  puw3:      lane L holds uw3p[o2=L&15][slot=(L>>4)*8+j]
// 3584..4096  pad

// ---------- merged prep: transposes + converts + packing ----------
__global__ __launch_bounds__(256) void k_prep(
    const float* __restrict__ x,
    const float* __restrict__ W0, const float* __restrict__ W1,
    const float* __restrict__ W2,
    const float* __restrict__ uw1, const float* __restrict__ ub1,
    const float* __restrict__ uw2, const float* __restrict__ ub2,
    const float* __restrict__ uw3, const float* __restrict__ b2,
    const float* __restrict__ ub3,
    u16* __restrict__ xb,
    u16* __restrict__ W0T, u16* __restrict__ W1T, u16* __restrict__ W2T,
    char* __restrict__ uwp, float* __restrict__ cb)
{
  __shared__ float tile[32][33];
  const int bid = blockIdx.x;
  const int tid = threadIdx.x;

  if (bid < 1312) {                       // weight transposes f32[K][N] -> bf16[N][K]
    const float* src; u16* dst; int K, N, kb, ob;
    if (bid < 256)       { src = W0; dst = W0T; K = 256;  N = 1024; int t = bid;        kb = (t & 7) * 32;  ob = (t >> 3) * 32; }
    else if (bid < 1280) { src = W1; dst = W1T; K = 1024; N = 1024; int t = bid - 256;  kb = (t & 31) * 32; ob = (t >> 5) * 32; }
    else                 { src = W2; dst = W2T; K = 1024; N = 16;   int t = bid - 1280; kb = t * 32;        ob = 0; }
    const int tx = tid & 31, ty = tid >> 5;
    for (int r = ty; r < 32; r += 8)
      if (ob + tx < N) tile[r][tx] = src[(size_t)(kb + r) * N + ob + tx];
    __syncthreads();
    for (int r = ty; r < 32; r += 8)
      if (ob + r < N) dst[(size_t)(ob + r) * K + kb + tx] = f2bf(tile[tx][r]);
  } else if (bid < 5408) {                // x -> bf16
    const int idx = ((bid - 1312) * 256 + tid) * 4;
    const float4 v = *(const float4*)&x[idx];
    u16x4 o4 = { f2bf(v.x), f2bf(v.y), f2bf(v.z), f2bf(v.w) };
    *(u16x4*)&xb[idx] = o4;
  } else if (bid < 5664) {                // uw2 -> puw2 fragments
    const int e = ((bid - 5408) * 256 + tid) * 4;
    const float4 v = *(const float4*)&uw2[e];
    const int i = e >> 10, f = (e >> 5) & 31, o = e & 31;
    const float vv[4] = { v.x, v.y, v.z, v.w };
    u16* blob16 = (u16*)(uwp + (size_t)i * 4096);
#pragma unroll
    for (int d = 0; d < 4; ++d) {
      const int oo = o + d;
      const int lane = ((f >> 3) << 4) | (oo & 15);
      blob16[256 + (oo >> 4) * 512 + lane * 8 + (f & 7)] = f2bf(vv[d]);
    }
  } else if (bid < 5792) {                // uw3 -> puw3 fragments (k-slot perm)
    const int e = ((bid - 5664) * 256 + tid) * 4;
    const float4 v = *(const float4*)&uw3[e];
    const int i = e >> 9, f = (e >> 4) & 31, o2 = e & 15;
    const int s = (f < 16) ? (((f >> 2) << 3) + (f & 3))
                           : ((((f - 16) >> 2) << 3) + 4 + (f & 3));
    const float vv[4] = { v.x, v.y, v.z, v.w };
    u16* blob16 = (u16*)(uwp + (size_t)i * 4096);
#pragma unroll
    for (int d = 0; d < 4; ++d)
      blob16[1280 + ((s >> 3) * 16 + o2 + d) * 8 + (s & 7)] = f2bf(vv[d]);
  } else if (bid < 5816) {                // uw1/ub1/ub2 f32 copy into blobs
    const int e4 = (bid - 5792) * 256 + tid;      // float4 index, 0..6143
    const int i = e4 / 24, r4 = e4 % 24;
    const float* src = (r4 < 8)  ? &uw1[i * 32 + r4 * 4]
                     : (r4 < 16) ? &ub1[i * 32 + (r4 - 8) * 4]
                                 : &ub2[i * 32 + (r4 - 16) * 4];
    *(float4*)(uwp + (size_t)i * 4096 + r4 * 16) = *(const float4*)src;
  } else {                                // cb[o] = b2[o] + sum_i ub3[i][o]
    __shared__ float red[16][16];
    const int ig = tid >> 4, o = tid & 15;
    float s = 0.f;
#pragma unroll
    for (int k = 0; k < 16; ++k) s += ub3[(ig * 16 + k) * 16 + o];
    red[ig][o] = s;
    __syncthreads();
    if (tid < 16) {
      float t = b2[tid];
#pragma unroll
      for (int k = 0; k < 16; ++k) t += red[k][tid];
      cb[tid] = t;
    }
  }
}

// ---------- MFMA GEMM: C = relu(A @ B^T + bias), bf16 in/out, fp32 acc ----------
__global__ __launch_bounds__(256, 2) void k_gemm(
    const u16* __restrict__ A, const u16* __restrict__ BT,
    const float* __restrict__ bias, u16* __restrict__ C,
    int M, int N, int K)
{
  const int tid = threadIdx.x;
  const int lane = tid & 63, wid = tid >> 6;
  const int l15 = lane & 15, g = lane >> 4;
  const int nbn = N >> 7;
  const int nwg = gridDim.x;
  int logical = blockIdx.x;
  if ((nwg & 7) == 0) {                       // bijective XCD swizzle
    const int q = nwg >> 3;
    logical = (logical & 7) * q + (logical >> 3);
  }
  const int bm = logical / nbn, bn = logical % nbn;
  const size_t rb = (size_t)bm * 128, cbase = (size_t)bn * 128;

  __shared__ __align__(16) u16 As[128 * 32];
  __shared__ __align__(16) u16 Bs[128 * 32];

  const int wr = (wid >> 1) * 64, wc = (wid & 1) * 64;
  f32x4 acc[4][4] = {};

  for (int kt = 0; kt < K; kt += 32) {
#pragma unroll
    for (int it = 0; it < 2; ++it) {
      const int s = it * 256 + tid;
      const int row = s >> 2, kc = s & 3;
      gload_lds16(&A[(rb + row) * K + kt + kc * 8], &As[s * 8]);
      gload_lds16(&BT[(cbase + row) * K + kt + kc * 8], &Bs[s * 8]);
    }
    __syncthreads();
    short8 a[4], b[4];
#pragma unroll
    for (int m = 0; m < 4; ++m)
      a[m] = *(const short8*)&As[(wr + m * 16 + l15) * 32 + g * 8];
#pragma unroll
    for (int n = 0; n < 4; ++n)
      b[n] = *(const short8*)&Bs[(wc + n * 16 + l15) * 32 + g * 8];
#pragma unroll
    for (int m = 0; m < 4; ++m)
#pragma unroll
      for (int n = 0; n < 4; ++n)
        acc[m][n] = mfma_s8(a[m], b[n], acc[m][n]);
    __syncthreads();
  }

#pragma unroll
  for (int n = 0; n < 4; ++n) {
    const int col = (int)cbase + wc + n * 16 + l15;
    const float bv = bias[col];
#pragma unroll
    for (int m = 0; m < 4; ++m) {
#pragma unroll
      for (int r = 0; r < 4; ++r) {
        const int row = (int)rb + wr + m * 16 + g * 4 + r;
        float v = acc[m][n][r] + bv;
        v = fmaxf(v, 0.f);
        C[(size_t)row * N + col] = f2bf(v);
      }
    }
  }
}

// ---------- uni MLPs + final layer (H1 @ W2^T), 8 chunks ----------
// grid = 1024: blockIdx = rowblk*8 + chunk. 4 waves x 32 batch rows (2 frags).
// All MFMAs operand-swapped: D[out][batch]; b = lane&15, out = 4*(lane>>4)+r.
// Depth-2 software pipeline on the packed weight blobs (two named register
// buffers A/B -- no runtime indexing), xv prefetched one iteration ahead,
// ub2 folded into the layer-2 MFMA accumulator init.
__global__ __launch_bounds__(256, 4) void k_uni(
    const float* __restrict__ x,
    const char* __restrict__ uwp,
    const u16* __restrict__ H1, const u16* __restrict__ W2T,
    float* __restrict__ part)
{
  const int tid = threadIdx.x, lane = tid & 63, wid = tid >> 6;
  const int l15 = lane & 15, g = lane >> 4;
  const int chunk = blockIdx.x & 7, rowblk = blockIdx.x >> 3;
  const int rb_blk = rowblk * 128;
  const int rb = rb_blk + wid * 32;
  const int i0 = chunk * 32;

  __shared__ __align__(16) float xt[128][36];   // x tile f32, padded
  {
    const int r0 = tid >> 3, c4 = (tid & 7) << 2;
#pragma unroll
    for (int rr = 0; rr < 128; rr += 32)
      *(float4*)&xt[rr + r0][c4] =
          *(const float4*)&x[(size_t)(rb_blk + rr + r0) * NINP + i0 + c4];
  }
  __syncthreads();

  const f32x4 zero4 = {0.f, 0.f, 0.f, 0.f};
  f32x4 acc0 = zero4, acc1 = zero4;
  const float* xr0 = &xt[wid * 32 + l15][0];
  const float* xr1 = &xt[wid * 32 + 16 + l15][0];

  // pipeline register buffers (named, statically indexed)
  f32x4 w1loA, w1hiA, b1loA, b1hiA, bb0A, bb1A; bf16x8 bv0A, bv1A, b3A;
  f32x4 w1loB, w1hiB, b1loB, b1hiB, bb0B, bb1B; bf16x8 bv0B, bv1B, b3B;

#define LOADW(S, P) do {                                       \
    const char* _p = (P);                                      \
    w1lo##S = *(const f32x4*)(_p + g * 32);                    \
    w1hi##S = *(const f32x4*)(_p + g * 32 + 16);               \
    b1lo##S = *(const f32x4*)(_p + 128 + g * 32);              \
    b1hi##S = *(const f32x4*)(_p + 128 + g * 32 + 16);         \
    bb0##S  = *(const f32x4*)(_p + 256 + g * 16);              \
    bb1##S  = *(const f32x4*)(_p + 320 + g * 16);              \
    bv0##S  = *(const bf16x8*)(_p + 512 + lane * 16);          \
    bv1##S  = *(const bf16x8*)(_p + 1536 + lane * 16);         \
    b3##S   = *(const bf16x8*)(_p + 2560 + lane * 16);         \
  } while (0)

#define COMPUTE(S, XV0, XV1) do {                                        \
    bf16x8 af0, af1;                                                     \
    _Pragma("unroll")                                                    \
    for (int j = 0; j < 4; ++j) {                                        \
      af0[j]     = (__bf16)fmaxf(fmaf(XV0, w1lo##S[j], b1lo##S[j]), 0.f);\
      af0[4 + j] = (__bf16)fmaxf(fmaf(XV0, w1hi##S[j], b1hi##S[j]), 0.f);\
      af1[j]     = (__bf16)fmaxf(fmaf(XV1, w1lo##S[j], b1lo##S[j]), 0.f);\
      af1[4 + j] = (__bf16)fmaxf(fmaf(XV1, w1hi##S[j], b1hi##S[j]), 0.f);\
    }                                                                    \
    const f32x4 d00 = mfma_bb(bv0##S, af0, bb0##S);                      \
    const f32x4 d10 = mfma_bb(bv1##S, af0, bb1##S);                      \
    const f32x4 d01 = mfma_bb(bv0##S, af1, bb0##S);                      \
    const f32x4 d11 = mfma_bb(bv1##S, af1, bb1##S);                      \
    bf16x8 h20, h21;                                                     \
    _Pragma("unroll")                                                    \
    for (int j = 0; j < 4; ++j) {                                        \
      h20[j]     = (__bf16)fmaxf(d00[j], 0.f);                           \
      h20[4 + j] = (__bf16)fmaxf(d10[j], 0.f);                           \
      h21[j]     = (__bf16)fmaxf(d01[j], 0.f);                           \
      h21[4 + j] = (__bf16)fmaxf(d11[j], 0.f);                           \
    }                                                                    \
    acc0 = mfma_bb(b3##S, h20, acc0);                                    \
    acc1 = mfma_bb(b3##S, h21, acc1);                                    \
  } while (0)

  LOADW(A, uwp + (size_t)i0 * 4096);
  LOADW(B, uwp + (size_t)(i0 + 1) * 4096);
  float xa0 = xr0[0], xa1 = xr1[0];
  float xb0 = xr0[1], xb1 = xr1[1];

#pragma unroll 2
  for (int ii = 0; ii < 32; ii += 2) {
    const int n2 = (ii + 2) & 31, n3 = (ii + 3) & 31;   // wrapped prefetch idx
    const int p2 = i0 + ii + 2, p3 = i0 + ii + 3;
    const size_t o2 = (size_t)(p2 < 256 ? p2 : 255) * 4096;
    const size_t o3 = (size_t)(p3 < 256 ? p3 : 255) * 4096;
    COMPUTE(A, xa0, xa1);
    LOADW(A, uwp + o2);                 // prefetch feature ii+2
    xa0 = xr0[n2]; xa1 = xr1[n2];
    COMPUTE(B, xb0, xb1);
    LOADW(B, uwp + o3);                 // prefetch feature ii+3
    xb0 = xr0[n3]; xb1 = xr1[n3];
  }
#undef LOADW
#undef COMPUTE

  // final-layer K-chunk: acc[o2][b] += W2T @ H1^T
  {
    const int kb0 = chunk * 128;
#pragma unroll
    for (int kk = 0; kk < 4; ++kk) {
      const int kb = kb0 + kk * 32;
      const bf16x8 a0 = __builtin_bit_cast(bf16x8,
          *(const i32x4*)&H1[(size_t)(rb + l15) * HID + kb + g * 8]);
      const bf16x8 a1 = __builtin_bit_cast(bf16x8,
          *(const i32x4*)&H1[(size_t)(rb + 16 + l15) * HID + kb + g * 8]);
      const bf16x8 bv = __builtin_bit_cast(bf16x8,
          *(const i32x4*)&W2T[l15 * HID + kb + g * 8]);
      acc0 = mfma_bb(bv, a0, acc0);
      acc1 = mfma_bb(bv, a1, acc1);
    }
  }

  // acc*[r] = u[b=l15(+16)][o2=4g+r] -> contiguous f32x4 stores
  float* p = part + ((size_t)chunk * BATCH + rb) * NOUT;
  *(f32x4*)&p[l15 * 16 + g * 4] = acc0;
  *(f32x4*)&p[(16 + l15) * 16 + g * 4] = acc1;
}

// ---------- reduce 8 partials + cb -> out ----------
__global__ __launch_bounds__(256) void k_reduce(
    const float* __restrict__ part, const float* __restrict__ cb,
    float* __restrict__ out)
{
  const int j4 = blockIdx.x * 256 + threadIdx.x;   // 65536 float4's
  const float4 c = ((const float4*)cb)[j4 & 3];
  const float4* p = (const float4*)part;
  float rx = c.x, ry = c.y, rz = c.z, rw = c.w;
#pragma unroll
  for (int cc = 0; cc < 8; ++cc) {
    const float4 a = p[cc * 65536 + j4];
    rx += a.x; ry += a.y; rz += a.z; rw += a.w;
  }
  float4 r; r.x = rx; r.y = ry; r.z = rz; r.w = rw;
  ((float4*)out)[j4] = r;
}

extern "C" void kernel_launch(void* const* d_in, const int* in_sizes, int n_in,
                              void* d_out, int out_size, void* d_ws, size_t ws_size,
                              hipStream_t stream) {
  (void)in_sizes; (void)n_in; (void)out_size; (void)ws_size;
  const float* x   = (const float*)d_in[0];
  const float* W0  = (const float*)d_in[1];
  const float* b0  = (const float*)d_in[2];
  const float* W1  = (const float*)d_in[3];
  const float* b1  = (const float*)d_in[4];
  const float* W2  = (const float*)d_in[5];
  const float* b2  = (const float*)d_in[6];
  const float* uw1 = (const float*)d_in[7];
  const float* ub1 = (const float*)d_in[8];
  const float* uw2 = (const float*)d_in[9];
  const float* ub2 = (const float*)d_in[10];
  const float* uw3 = (const float*)d_in[11];
  const float* ub3 = (const float*)d_in[12];
  float* out = (float*)d_out;

  char* ws = (char*)d_ws;
  u16*   H0   = (u16*)(ws + OFF_H0);
  u16*   H1   = (u16*)(ws + OFF_H1);
  u16*   xb   = (u16*)(ws + OFF_XB);
  u16*   W0T  = (u16*)(ws + OFF_W0T);
  u16*   W1T  = (u16*)(ws + OFF_W1T);
  u16*   W2T  = (u16*)(ws + OFF_W2T);
  char*  uwp  = (char*)(ws + OFF_UWP);
  float* cb   = (float*)(ws + OFF_CB);
  float* part = (float*)(ws + OFF_PART);

  k_prep<<<5817, 256, 0, stream>>>(x, W0, W1, W2, uw1, ub1, uw2, ub2, uw3,
                                   b2, ub3, xb, W0T, W1T, W2T, uwp, cb);
  k_gemm<<<1024, 256, 0, stream>>>(xb, W0T, b0, H0, BATCH, HID, NINP);
  k_gemm<<<1024, 256, 0, stream>>>(H0, W1T, b1, H1, BATCH, HID, HID);
  k_uni<<<1024, 256, 0, stream>>>(x, uwp, H1, W2T, part);
  k_reduce<<<256, 256, 0, stream>>>(part, cb, out);
}